// Round 5
// baseline (2003.678 us; speedup 1.0000x reference)
//
#include <hip/hip_runtime.h>

// GaussianSoftmax: out[b,n,m] = softmax_m( exp( exp(-max(||x_n-x_m||^2,0)/sigma) ) )
// X: [8, 4096, 16] fp32, sigma: [1], out: [8, 4096, 4096] fp32 (512 MiB).
// R5: two-pass recompute. Pass 1 (sums): row sums of e only -> inv[b][n]
// (128 KB), no output traffic. Pass 2 (write): recompute e, scale by inv,
// stream straight to global from registers -- no 64KiB LDS staging, no
// compute/store barrier, writes overlap compute per-wave. Both passes use
// the R4-proven register profile (TN=4, q in VGPRs, ~110 live < 128 cap).

constexpr int Bn  = 8;
constexpr int N   = 4096;
constexpr int F   = 16;
constexpr int TN  = 4;      // rows per block
constexpr int BLK = 256;    // 4 waves/block
constexpr int WPB = BLK / 64;
constexpr int GROUPS = (N / 4) / BLK;   // 4 float4-column groups per thread

__global__ __launch_bounds__(256)
void pack_kernel(const float* __restrict__ X, float* __restrict__ Xt) {
    const int b = blockIdx.y;
    const int m = blockIdx.x * 256 + threadIdx.x;
    const float4* src = (const float4*)(X + ((size_t)b * N + m) * F);
    const float4 v0 = src[0], v1 = src[1], v2 = src[2], v3 = src[3];
    const float x[F] = {v0.x, v0.y, v0.z, v0.w, v1.x, v1.y, v1.z, v1.w,
                        v2.x, v2.y, v2.z, v2.w, v3.x, v3.y, v3.z, v3.w};
    float* dst = Xt + (size_t)b * F * N + m;
    #pragma unroll
    for (int f = 0; f < F; ++f) dst[(size_t)f * N] = x[f];   // coalesced dwords
}

__device__ __forceinline__ float dot4(float4 a, float4 b) {
    return fmaf(a.x, b.x, fmaf(a.y, b.y, fmaf(a.z, b.z, a.w * b.w)));
}

__device__ __forceinline__ float gse(float d, float base, float nis) {
    float sqd = fmaxf(fmaf(-2.0f, d, base), 0.0f);
    return __expf(__expf(sqd * nis));
}

template <bool WRITE>
__global__ __launch_bounds__(BLK, 4)
void gs_pass(const float* __restrict__ X, const float* __restrict__ Xt,
             const float* __restrict__ sigma_p, float* __restrict__ invsum,
             float* __restrict__ out) {
    __shared__ float red[TN][WPB];

    const int tid = threadIdx.x;
    const int b   = blockIdx.y;
    const int n0  = blockIdx.x * TN;
    const float* Xb = X + (size_t)b * N * F;

    // Query rows: thread-uniform float4 loads -> scalar regs (R4-proven).
    float4 q0[TN], q1[TN], q2[TN], q3[TN];
    float  sqn[TN];
    #pragma unroll
    for (int r = 0; r < TN; ++r) {
        const float4* qp = (const float4*)(Xb + (size_t)(n0 + r) * F);
        q0[r] = qp[0]; q1[r] = qp[1]; q2[r] = qp[2]; q3[r] = qp[3];
        sqn[r] = dot4(q0[r], q0[r]) + dot4(q1[r], q1[r])
               + dot4(q2[r], q2[r]) + dot4(q3[r], q3[r]);
    }
    const float nis = -1.0f / sigma_p[0];

    float inv[TN];
    if (WRITE) {
        #pragma unroll
        for (int r = 0; r < TN; ++r) inv[r] = invsum[(size_t)b * N + n0 + r];
    }

    const float4* Xt4 = (const float4*)(Xt + (size_t)b * F * N);
    float sums[TN] = {0.f, 0.f, 0.f, 0.f};

    #pragma unroll
    for (int g = 0; g < GROUPS; ++g) {
        const int c4 = g * BLK + tid;   // float4-column index

        float4 d[TN];
        #pragma unroll
        for (int r = 0; r < TN; ++r) d[r] = make_float4(0.f, 0.f, 0.f, 0.f);
        float4 sq = make_float4(0.f, 0.f, 0.f, 0.f);

        #pragma unroll
        for (int fb = 0; fb < F / 4; ++fb) {      // f-block of 4 features
            float4 v0 = Xt4[(size_t)(fb * 4 + 0) * (N / 4) + c4];
            float4 v1 = Xt4[(size_t)(fb * 4 + 1) * (N / 4) + c4];
            float4 v2 = Xt4[(size_t)(fb * 4 + 2) * (N / 4) + c4];
            float4 v3 = Xt4[(size_t)(fb * 4 + 3) * (N / 4) + c4];

            #pragma unroll
            for (int k = 0; k < 4; ++k) {
                const float4 w = (k == 0) ? v0 : (k == 1) ? v1 : (k == 2) ? v2 : v3;
                sq.x = fmaf(w.x, w.x, sq.x);
                sq.y = fmaf(w.y, w.y, sq.y);
                sq.z = fmaf(w.z, w.z, sq.z);
                sq.w = fmaf(w.w, w.w, sq.w);
                #pragma unroll
                for (int r = 0; r < TN; ++r) {
                    const float4 qb = (fb == 0) ? q0[r] : (fb == 1) ? q1[r]
                                    : (fb == 2) ? q2[r] : q3[r];
                    const float qf = (k == 0) ? qb.x : (k == 1) ? qb.y
                                   : (k == 2) ? qb.z : qb.w;
                    d[r].x = fmaf(qf, w.x, d[r].x);
                    d[r].y = fmaf(qf, w.y, d[r].y);
                    d[r].z = fmaf(qf, w.z, d[r].z);
                    d[r].w = fmaf(qf, w.w, d[r].w);
                }
            }
        }

        #pragma unroll
        for (int r = 0; r < TN; ++r) {
            float4 e;
            e.x = gse(d[r].x, sqn[r] + sq.x, nis);
            e.y = gse(d[r].y, sqn[r] + sq.y, nis);
            e.z = gse(d[r].z, sqn[r] + sq.z, nis);
            e.w = gse(d[r].w, sqn[r] + sq.w, nis);
            if (WRITE) {
                float4 o = make_float4(e.x * inv[r], e.y * inv[r],
                                       e.z * inv[r], e.w * inv[r]);
                ((float4*)(out + ((size_t)b * N + n0 + r) * N))[c4] = o;
            } else {
                sums[r] += (e.x + e.y) + (e.z + e.w);
            }
        }
    }

    if (!WRITE) {
        #pragma unroll
        for (int r = 0; r < TN; ++r) {
            float s = sums[r];
            #pragma unroll
            for (int off = 32; off > 0; off >>= 1) s += __shfl_down(s, off, 64);
            if ((tid & 63) == 0) red[r][tid >> 6] = s;
        }
        __syncthreads();
        if (tid < TN) {
            float t = 0.f;
            #pragma unroll
            for (int w = 0; w < WPB; ++w) t += red[tid][w];
            invsum[(size_t)b * N + n0 + tid] = 1.0f / t;
        }
    }
}

extern "C" void kernel_launch(void* const* d_in, const int* in_sizes, int n_in,
                              void* d_out, int out_size, void* d_ws, size_t ws_size,
                              hipStream_t stream) {
    const float* X     = (const float*)d_in[0];
    const float* sigma = (const float*)d_in[1];
    float* out         = (float*)d_out;
    float* Xt          = (float*)d_ws;                        // 2 MiB
    float* invsum      = (float*)d_ws + (size_t)Bn * F * N;   // +128 KiB

    pack_kernel<<<dim3(N / 256, Bn), 256, 0, stream>>>(X, Xt);
    gs_pass<false><<<dim3(N / TN, Bn), BLK, 0, stream>>>(X, Xt, sigma, invsum, out);
    gs_pass<true ><<<dim3(N / TN, Bn), BLK, 0, stream>>>(X, Xt, sigma, invsum, out);
}

// Round 6
// 666.776 us; speedup vs baseline: 3.0050x; 3.0050x over previous
//
#include <hip/hip_runtime.h>

// GaussianSoftmax: out[b,n,m] = softmax_m( exp( exp(-max(||x_n-x_m||^2,0)/sigma) ) )
// X: [8, 4096, 16] fp32, sigma: [1], out: [8, 4096, 4096] fp32 (512 MiB).
// R6 = R5 two-pass recompute with the spill killed by construction:
//  - q (wave-uniform, 64 floats) forced into SGPRs via readfirstlane
//  - amdgpu_waves_per_eu(2,4): allocator plans for <=4 waves/EU (>=128 VGPR
//    budget) instead of starving to 64 VGPRs and spilling (R3/R5 failure)
//  - remaining VGPR live state ~70: v(16)+d(16)+sq(4)+misc
// Pass 1: row sums only -> invsum (128 KB). Pass 2: recompute e, scale,
// stream straight to global; no big LDS, no phase barriers.

constexpr int Bn  = 8;
constexpr int N   = 4096;
constexpr int F   = 16;
constexpr int TN  = 4;      // rows per block
constexpr int BLK = 256;    // 4 waves/block
constexpr int WPB = BLK / 64;
constexpr int GROUPS = (N / 4) / BLK;   // 4 float4-column groups per thread

__global__ __launch_bounds__(256)
void pack_kernel(const float* __restrict__ X, float* __restrict__ Xt) {
    const int b = blockIdx.y;
    const int m = blockIdx.x * 256 + threadIdx.x;
    const float4* src = (const float4*)(X + ((size_t)b * N + m) * F);
    const float4 v0 = src[0], v1 = src[1], v2 = src[2], v3 = src[3];
    const float x[F] = {v0.x, v0.y, v0.z, v0.w, v1.x, v1.y, v1.z, v1.w,
                        v2.x, v2.y, v2.z, v2.w, v3.x, v3.y, v3.z, v3.w};
    float* dst = Xt + (size_t)b * F * N + m;
    #pragma unroll
    for (int f = 0; f < F; ++f) dst[(size_t)f * N] = x[f];   // coalesced dwords
}

__device__ __forceinline__ float uni(float x) {  // force SGPR residency
    return __int_as_float(__builtin_amdgcn_readfirstlane(__float_as_int(x)));
}

__device__ __forceinline__ float gse(float d, float base, float nis) {
    float sqd = fmaxf(fmaf(-2.0f, d, base), 0.0f);
    return __expf(__expf(sqd * nis));
}

template <bool WRITE>
__global__ __launch_bounds__(BLK)
__attribute__((amdgpu_waves_per_eu(2, 4)))
void gs_pass(const float* __restrict__ X, const float* __restrict__ Xt,
             const float* __restrict__ sigma_p, float* __restrict__ invsum,
             float* __restrict__ out) {
    __shared__ float red[TN][WPB];

    const int tid = threadIdx.x;
    const int b   = blockIdx.y;
    const int n0  = blockIdx.x * TN;
    const float* Xb = X + (size_t)b * N * F;

    // Query rows -> SGPRs (wave-uniform values, readfirstlane-pinned).
    float q[TN][F];
    float sqn[TN];
    #pragma unroll
    for (int r = 0; r < TN; ++r) {
        float s = 0.f;
        #pragma unroll
        for (int f = 0; f < F; ++f) {
            const float qq = uni(Xb[(size_t)(n0 + r) * F + f]);
            q[r][f] = qq;
            s = fmaf(qq, qq, s);
        }
        sqn[r] = uni(s);
    }
    const float nis = uni(-1.0f / sigma_p[0]);

    float inv[TN];
    if (WRITE) {
        #pragma unroll
        for (int r = 0; r < TN; ++r) inv[r] = uni(invsum[(size_t)b * N + n0 + r]);
    }

    const float4* Xt4 = (const float4*)(Xt + (size_t)b * F * N);
    float sums[TN] = {0.f, 0.f, 0.f, 0.f};

    #pragma unroll 1
    for (int g = 0; g < GROUPS; ++g) {
        const int c4 = g * BLK + tid;   // float4-column index

        float4 d[TN];
        #pragma unroll
        for (int r = 0; r < TN; ++r) d[r] = make_float4(0.f, 0.f, 0.f, 0.f);
        float4 sq = make_float4(0.f, 0.f, 0.f, 0.f);

        #pragma unroll
        for (int fb = 0; fb < F / 4; ++fb) {      // f-block of 4 features
            float4 v0 = Xt4[(size_t)(fb * 4 + 0) * (N / 4) + c4];
            float4 v1 = Xt4[(size_t)(fb * 4 + 1) * (N / 4) + c4];
            float4 v2 = Xt4[(size_t)(fb * 4 + 2) * (N / 4) + c4];
            float4 v3 = Xt4[(size_t)(fb * 4 + 3) * (N / 4) + c4];

            #pragma unroll
            for (int k = 0; k < 4; ++k) {
                const float4 w = (k == 0) ? v0 : (k == 1) ? v1 : (k == 2) ? v2 : v3;
                sq.x = fmaf(w.x, w.x, sq.x);
                sq.y = fmaf(w.y, w.y, sq.y);
                sq.z = fmaf(w.z, w.z, sq.z);
                sq.w = fmaf(w.w, w.w, sq.w);
                #pragma unroll
                for (int r = 0; r < TN; ++r) {
                    const float qf = q[r][fb * 4 + k];   // SGPR operand
                    d[r].x = fmaf(qf, w.x, d[r].x);
                    d[r].y = fmaf(qf, w.y, d[r].y);
                    d[r].z = fmaf(qf, w.z, d[r].z);
                    d[r].w = fmaf(qf, w.w, d[r].w);
                }
            }
        }

        #pragma unroll
        for (int r = 0; r < TN; ++r) {
            float4 e;
            e.x = gse(d[r].x, sqn[r] + sq.x, nis);
            e.y = gse(d[r].y, sqn[r] + sq.y, nis);
            e.z = gse(d[r].z, sqn[r] + sq.z, nis);
            e.w = gse(d[r].w, sqn[r] + sq.w, nis);
            if (WRITE) {
                float4 o = make_float4(e.x * inv[r], e.y * inv[r],
                                       e.z * inv[r], e.w * inv[r]);
                ((float4*)(out + ((size_t)b * N + n0 + r) * N))[c4] = o;
            } else {
                sums[r] += (e.x + e.y) + (e.z + e.w);
            }
        }
    }

    if (!WRITE) {
        #pragma unroll
        for (int r = 0; r < TN; ++r) {
            float s = sums[r];
            #pragma unroll
            for (int off = 32; off > 0; off >>= 1) s += __shfl_down(s, off, 64);
            if ((tid & 63) == 0) red[r][tid >> 6] = s;
        }
        __syncthreads();
        if (tid < TN) {
            float t = 0.f;
            #pragma unroll
            for (int w = 0; w < WPB; ++w) t += red[tid][w];
            invsum[(size_t)b * N + n0 + tid] = 1.0f / t;
        }
    }
}

extern "C" void kernel_launch(void* const* d_in, const int* in_sizes, int n_in,
                              void* d_out, int out_size, void* d_ws, size_t ws_size,
                              hipStream_t stream) {
    const float* X     = (const float*)d_in[0];
    const float* sigma = (const float*)d_in[1];
    float* out         = (float*)d_out;
    float* Xt          = (float*)d_ws;                        // 2 MiB
    float* invsum      = (float*)d_ws + (size_t)Bn * F * N;   // +128 KiB

    pack_kernel<<<dim3(N / 256, Bn), 256, 0, stream>>>(X, Xt);
    gs_pass<false><<<dim3(N / TN, Bn), BLK, 0, stream>>>(X, Xt, sigma, invsum, out);
    gs_pass<true ><<<dim3(N / TN, Bn), BLK, 0, stream>>>(X, Xt, sigma, invsum, out);
}